// Round 4
// baseline (590.306 us; speedup 1.0000x reference)
//
#include <hip/hip_runtime.h>
#include <math.h>

#define B_ 8
#define T_ 12
#define N_ 200
#define R_ 1600    // B*N
#define NN_ 40000  // N*N

__device__ __forceinline__ float sigm(float v) { return 1.f / (1.f + expf(-v)); }

// ======== Phase A: dy-GRU chain + P/Q projections (bias folded into P) ====
__global__ void __launch_bounds__(256) k_dyall(
        const float* __restrict__ x,  const float* __restrict__ nf,
        const float* __restrict__ Ws2d, const float* __restrict__ bs2d,
        const float* __restrict__ Wrz,  const float* __restrict__ brz,
        const float* __restrict__ Wh,   const float* __restrict__ bh,
        const float* __restrict__ Wc2,  const float* __restrict__ Wm2,
        const float* __restrict__ bc2,  const float* __restrict__ bm2,
        float* __restrict__ Pc, float* __restrict__ Qc,
        float* __restrict__ Pm, float* __restrict__ Qm,
        float* __restrict__ state) {
    __shared__ float sWs2d[64 * 32], sWrz[33 * 64], sWh[33 * 32];
    __shared__ float sWc2[64 * 32], sWm2[64 * 32];
    __shared__ float sbrz[64], sbh[32], sbs2d[32], sbc2[32], sbm2[32];
    __shared__ float nfs[4][64], dy[4][32], in1[4][33], in2[4][33], rz[4][64], s4[4][32];
    int bk = blockIdx.x, tid = threadIdx.x;
    int w = tid >> 6, o = tid & 63;
    int row = bk * 4 + w, b = row / N_, n = row % N_;
    state[bk * 256 + tid] = 0.f;
    for (int idx = tid; idx < 2048; idx += 256) sWs2d[idx] = Ws2d[idx];
    for (int idx = tid; idx < 2112; idx += 256) sWrz[idx] = Wrz[idx];
    for (int idx = tid; idx < 1056; idx += 256) sWh[idx] = Wh[idx];
    for (int idx = tid; idx < 2048; idx += 256) { sWc2[idx] = Wc2[idx]; sWm2[idx] = Wm2[idx]; }
    if (tid < 64) sbrz[tid] = brz[tid];
    if (tid < 32) { sbh[tid] = bh[tid]; sbs2d[tid] = bs2d[tid];
                    sbc2[tid] = bc2[tid]; sbm2[tid] = bm2[tid]; }
    nfs[w][o] = nf[n * 64 + o];
    __syncthreads();
    if (o < 32) {
        float acc = sbs2d[o];
        #pragma unroll 8
        for (int i = 0; i < 64; ++i) acc += nfs[w][i] * sWs2d[i * 32 + o];
        dy[w][o] = acc;
    }
    __syncthreads();
    for (int t = 0; t < T_; ++t) {
        if (o == 0) { float v = x[((b * T_ + t) * N_ + n) * 2]; in1[w][0] = v; in2[w][0] = v; }
        if (o < 32) in1[w][o + 1] = dy[w][o];
        __syncthreads();
        float acc = sbrz[o];
        #pragma unroll
        for (int i = 0; i < 33; ++i) acc += in1[w][i] * sWrz[i * 64 + o];
        rz[w][o] = sigm(acc);
        __syncthreads();
        if (o < 32) in2[w][o + 1] = rz[w][o] * dy[w][o];
        __syncthreads();
        if (o < 32) {
            float h = sbh[o];
            #pragma unroll
            for (int i = 0; i < 33; ++i) h += in2[w][i] * sWh[i * 32 + o];
            h = tanhf(h);
            float z = rz[w][32 + o];
            float nd = z * dy[w][o] + (1.f - z) * h;
            dy[w][o] = nd;
            s4[w][o] = nd > 0.f ? nd : 0.f;
        }
        __syncthreads();
        size_t base = ((size_t)t * R_ + row) * 32;
        for (int idx = o; idx < 128; idx += 64) {
            int mat = idx >> 5, k = idx & 31;
            const float* W = (mat < 2) ? sWc2 : sWm2;
            int rb = (mat & 1) ? 32 : 0;
            float a = (mat == 0) ? sbc2[k] : (mat == 2) ? sbm2[k] : 0.f;
            #pragma unroll
            for (int i = 0; i < 32; ++i) a += s4[w][i] * W[(rb + i) * 32 + k];
            ((mat == 0) ? Pc : (mat == 1) ? Qc : (mat == 2) ? Pm : Qm)[base + k] = a;
        }
        __syncthreads();
    }
}

// ======== Phase B: adjacency — 32x16 tile, 2 output rows/thread ====
__global__ void __launch_bounds__(256) k_pairall(
        const float* __restrict__ Pc, const float* __restrict__ Qc,
        const float* __restrict__ Pm, const float* __restrict__ Qm,
        const float* __restrict__ Wc1, const float* __restrict__ bc1,
        const float* __restrict__ Wm1, const float* __restrict__ bm1,
        float* __restrict__ out) {
    __shared__ float sPc[32][36], sPm[32][36], sQc[16][36], sQm[16][36];
    int z = blockIdx.z;            // t*8 + b
    int i0 = blockIdx.x * 32, j0 = blockIdx.y * 16;
    int tid = threadIdx.y * 16 + threadIdx.x;
    size_t tb = (size_t)z * N_;
    float4 z4 = make_float4(0.f, 0.f, 0.f, 0.f);
    {   // stage P: 32 rows x 8 float4 (exactly 256 slots)
        int r = tid >> 3, q = tid & 7;
        int gi = i0 + r;
        *(float4*)&sPc[r][4 * q] = (gi < N_) ? *(const float4*)&Pc[(tb + gi) * 32 + 4 * q] : z4;
        *(float4*)&sPm[r][4 * q] = (gi < N_) ? *(const float4*)&Pm[(tb + gi) * 32 + 4 * q] : z4;
    }
    if (tid < 128) {   // stage Q: 16 rows x 8 float4
        int r = tid >> 3, q = tid & 7;
        int gj = j0 + r;
        *(float4*)&sQc[r][4 * q] = (gj < N_) ? *(const float4*)&Qc[(tb + gj) * 32 + 4 * q] : z4;
        *(float4*)&sQm[r][4 * q] = (gj < N_) ? *(const float4*)&Qm[(tb + gj) * 32 + 4 * q] : z4;
    }
    // W in registers (uniform -> scalar loads)
    float4 wc[8], wm[8];
    #pragma unroll
    for (int kg = 0; kg < 8; ++kg) {
        wc[kg] = *(const float4*)&Wc1[4 * kg];
        wm[kg] = *(const float4*)&Wm1[4 * kg];
    }
    __syncthreads();
    int ty = threadIdx.y, tx = threadIdx.x;
    int j = j0 + tx;
    float gA = 0.f, gB = 0.f, mA = 0.f, mB = 0.f;
    #pragma unroll
    for (int kg = 0; kg < 8; ++kg) {
        float4 qc = *(const float4*)&sQc[tx][4 * kg];
        float4 qm = *(const float4*)&sQm[tx][4 * kg];
        float4 pA = *(const float4*)&sPc[ty][4 * kg];
        float4 pB = *(const float4*)&sPc[16 + ty][4 * kg];
        float4 w  = wc[kg];
        gA += fmaxf(pA.x + qc.x, 0.f) * w.x + fmaxf(pA.y + qc.y, 0.f) * w.y
            + fmaxf(pA.z + qc.z, 0.f) * w.z + fmaxf(pA.w + qc.w, 0.f) * w.w;
        gB += fmaxf(pB.x + qc.x, 0.f) * w.x + fmaxf(pB.y + qc.y, 0.f) * w.y
            + fmaxf(pB.z + qc.z, 0.f) * w.z + fmaxf(pB.w + qc.w, 0.f) * w.w;
        float4 nA = *(const float4*)&sPm[ty][4 * kg];
        float4 nB = *(const float4*)&sPm[16 + ty][4 * kg];
        float4 v  = wm[kg];
        mA += fmaxf(nA.x + qm.x, 0.f) * v.x + fmaxf(nA.y + qm.y, 0.f) * v.y
            + fmaxf(nA.z + qm.z, 0.f) * v.z + fmaxf(nA.w + qm.w, 0.f) * v.w;
        mB += fmaxf(nB.x + qm.x, 0.f) * v.x + fmaxf(nB.y + qm.y, 0.f) * v.y
            + fmaxf(nB.z + qm.z, 0.f) * v.z + fmaxf(nB.w + qm.w, 0.f) * v.w;
    }
    if (j < N_) {
        float bg = bc1[0], bm = bm1[0];
        int iA = i0 + ty, iB = iA + 16;
        if (iA < N_) out[R_ + (((size_t)z * N_ + iA) * N_ + j)] = (gA + bg) * sigm(mA + bm);
        if (iB < N_) out[R_ + (((size_t)z * N_ + iB) * N_ + j)] = (gB + bg) * sigm(mB + bm);
    }
}

// ======== A2 = A @ A — 128x64 tile, 128 threads, 8x8 micro, BK=16 ========
// 16 FMA per ds_read_b128 while KEEPING 768 blocks (3 blocks/CU,
// 6 waves/CU) so barrier drains are filled — fixes R2's grid starvation.
__global__ void __launch_bounds__(128) k_a2(
        const float* __restrict__ Abase, float* __restrict__ Cbase, int nmat) {
    __shared__ float Ast[16][132];   // [k][i] transposed
    __shared__ float Bs[16][68];     // [k][j]
    int bx = blockIdx.x;
    int z = bx % nmat, tl = bx / nmat;      // z fastest => XCD-local matrices
    int i0 = (tl >> 2) * 128, j0 = (tl & 3) * 64;
    const float* Az = Abase + (size_t)z * NN_;
    float* Cz = Cbase + (size_t)z * NN_;
    int tid = threadIdx.x;                  // 128 threads
    int tx = tid & 7, ty = tid >> 3;        // tx: 8 col-groups, ty: 16 row-groups
    float4 acc[2][4][2];
    #pragma unroll
    for (int ai = 0; ai < 2; ++ai)
        #pragma unroll
        for (int r = 0; r < 4; ++r)
            #pragma unroll
            for (int ci = 0; ci < 2; ++ci) acc[ai][r][ci] = make_float4(0.f, 0.f, 0.f, 0.f);
    for (int k0 = 0; k0 < 208; k0 += 16) {
        // stage A transposed: 128 i x 16 k (512 float4, 4/thread)
        #pragma unroll
        for (int q = 0; q < 4; ++q) {
            int id = tid + 128 * q;           // 0..511
            int i = id >> 2, kq = (id & 3) * 4;
            int gi = i0 + i, gk = k0 + kq;
            float4 v = make_float4(0.f, 0.f, 0.f, 0.f);
            if (gi < N_ && gk < N_) v = *(const float4*)&Az[gi * N_ + gk];
            Ast[kq + 0][i] = v.x; Ast[kq + 1][i] = v.y;
            Ast[kq + 2][i] = v.z; Ast[kq + 3][i] = v.w;
        }
        // stage B: 16 k x 64 j (256 float4, 2/thread)
        #pragma unroll
        for (int q = 0; q < 2; ++q) {
            int id = tid + 128 * q;           // 0..255
            int k = id >> 4, jq = (id & 15) * 4;
            int gk = k0 + k, gj = j0 + jq;
            float4 v = make_float4(0.f, 0.f, 0.f, 0.f);
            if (gk < N_ && gj < N_) v = *(const float4*)&Az[gk * N_ + gj];
            *(float4*)&Bs[k][jq] = v;
        }
        __syncthreads();
        #pragma unroll
        for (int k = 0; k < 16; ++k) {
            float4 a0 = *(const float4*)&Ast[k][ty * 4];
            float4 a1 = *(const float4*)&Ast[k][64 + ty * 4];
            float4 b0 = *(const float4*)&Bs[k][tx * 4];
            float4 b1 = *(const float4*)&Bs[k][32 + tx * 4];
            #pragma unroll
            for (int ai = 0; ai < 2; ++ai) {
                float4 av = ai ? a1 : a0;
                #pragma unroll
                for (int ci = 0; ci < 2; ++ci) {
                    float4 bv = ci ? b1 : b0;
                    acc[ai][0][ci].x += av.x * bv.x; acc[ai][0][ci].y += av.x * bv.y;
                    acc[ai][0][ci].z += av.x * bv.z; acc[ai][0][ci].w += av.x * bv.w;
                    acc[ai][1][ci].x += av.y * bv.x; acc[ai][1][ci].y += av.y * bv.y;
                    acc[ai][1][ci].z += av.y * bv.z; acc[ai][1][ci].w += av.y * bv.w;
                    acc[ai][2][ci].x += av.z * bv.x; acc[ai][2][ci].y += av.z * bv.y;
                    acc[ai][2][ci].z += av.z * bv.z; acc[ai][2][ci].w += av.z * bv.w;
                    acc[ai][3][ci].x += av.w * bv.x; acc[ai][3][ci].y += av.w * bv.y;
                    acc[ai][3][ci].z += av.w * bv.z; acc[ai][3][ci].w += av.w * bv.w;
                }
            }
        }
        __syncthreads();
    }
    #pragma unroll
    for (int ai = 0; ai < 2; ++ai) {
        #pragma unroll
        for (int r = 0; r < 4; ++r) {
            int gi = i0 + ai * 64 + ty * 4 + r;
            if (gi >= N_) continue;
            #pragma unroll
            for (int ci = 0; ci < 2; ++ci) {
                int gj = j0 + ci * 32 + tx * 4;
                if (gj < N_) *(float4*)&Cz[gi * N_ + gj] = acc[ai][r][ci];
            }
        }
    }
}

// ======== xt-hops: xh[zl][i][4] = {A@x0, A@x1, A2@x0, A2@x1} ========
__global__ void __launch_bounds__(256) k_xh(
        const float* __restrict__ Abase, const float* __restrict__ A2base,
        const float* __restrict__ x, int z0, float* __restrict__ xh) {
    __shared__ float xtl[400];
    int zl = blockIdx.x, tid = threadIdx.x;
    int z = z0 + zl, t = z >> 3, b = z & 7;
    int w = tid >> 6, l = tid & 63;
    const float* xb = x + ((size_t)(b * T_ + t)) * N_ * 2;
    for (int idx = tid; idx < 400; idx += 256) xtl[idx] = xb[idx];
    __syncthreads();
    for (int it = 0; it < 50; ++it) {
        int i = it * 4 + w;
        float p0 = 0.f, p1 = 0.f, p2 = 0.f, p3 = 0.f;
        if (l < 50) {
            float4 a4 = *(const float4*)(Abase + (size_t)zl * NN_ + i * 200 + 4 * l);
            float4 c4 = *(const float4*)(A2base + (size_t)zl * NN_ + i * 200 + 4 * l);
            #pragma unroll
            for (int q = 0; q < 4; ++q) {
                float av = (&a4.x)[q], cv = (&c4.x)[q];
                float x0 = xtl[(4 * l + q) * 2], x1 = xtl[(4 * l + q) * 2 + 1];
                p0 += av * x0; p1 += av * x1; p2 += cv * x0; p3 += cv * x1;
            }
        }
        #pragma unroll
        for (int off = 32; off > 0; off >>= 1) {
            p0 += __shfl_down(p0, off); p1 += __shfl_down(p1, off);
            p2 += __shfl_down(p2, off); p3 += __shfl_down(p3, off);
        }
        if (l == 0) *(float4*)(xh + ((size_t)zl * N_ + i) * 4) = make_float4(p0, p1, p2, p3);
    }
}

// ======== K1: hops + ru gate -> rs, u (4 rows/block, 400 blocks) ========
// Hop split across 2 waves (jg halves) + LDS combine.
__global__ void __launch_bounds__(256) k_ru2(
        const float* __restrict__ At, const float* __restrict__ A2t,
        const float* __restrict__ xht,
        const float* __restrict__ x, int t, const float* __restrict__ state,
        const float* __restrict__ Wru, const float* __restrict__ bru,
        float* __restrict__ rs, float* __restrict__ ub) {
    __shared__ float sF[200 * 64];
    __shared__ float a4s[4 * 200], c4s[4 * 200];
    __shared__ float g8[4 * 132];
    __shared__ float g8p[2][4 * 132];
    __shared__ float xts[8];
    int bx = blockIdx.x;
    int b = bx & 7, i0 = (bx >> 3) * 4;      // XCD-local batches
    int tid = threadIdx.x;
    {
        const float4* stb = (const float4*)(state + (size_t)b * N_ * 64);
        float4* sFv = (float4*)sF;
        for (int idx = tid; idx < 3200; idx += 256) sFv[idx] = stb[idx];
        const float4* Ar = (const float4*)(At + ((size_t)b * N_ + i0) * 200);
        const float4* Cr = (const float4*)(A2t + ((size_t)b * N_ + i0) * 200);
        float4* av = (float4*)a4s; float4* cv = (float4*)c4s;
        for (int idx = tid; idx < 200; idx += 256) { av[idx] = Ar[idx]; cv[idx] = Cr[idx]; }
        if (tid < 8) xts[tid] = x[((size_t)(b * T_ + t) * N_ + i0 + (tid >> 1)) * 2 + (tid & 1)];
        if (tid >= 8 && tid < 24) {
            int l = tid - 8, rr = l >> 2, q = l & 3;
            g8[rr * 132 + ((q < 2) ? q : q + 64)] = xht[((size_t)b * N_ + i0 + rr) * 4 + q];
        }
    }
    __syncthreads();
    if (tid < 128) {   // hop: 2 waves, each 25 jg, both matrices
        int half = tid >> 6;
        int r = (tid >> 4) & 3, cg = tid & 15;
        const float* ar = a4s + r * 200 + half * 100;
        const float* cr = c4s + r * 200 + half * 100;
        const float* fbase = &sF[half * 100 * 64];
        float4 accA = make_float4(0.f, 0.f, 0.f, 0.f);
        float4 accC = make_float4(0.f, 0.f, 0.f, 0.f);
        #pragma unroll 5
        for (int jg = 0; jg < 25; ++jg) {
            float4 a4 = *(const float4*)&ar[4 * jg];
            float4 c4 = *(const float4*)&cr[4 * jg];
            const float* fb = fbase + (4 * jg) * 64 + 4 * cg;
            float4 v0 = *(const float4*)fb;
            float4 v1 = *(const float4*)(fb + 64);
            float4 v2 = *(const float4*)(fb + 128);
            float4 v3 = *(const float4*)(fb + 192);
            accA.x += a4.x * v0.x + a4.y * v1.x + a4.z * v2.x + a4.w * v3.x;
            accA.y += a4.x * v0.y + a4.y * v1.y + a4.z * v2.y + a4.w * v3.y;
            accA.z += a4.x * v0.z + a4.y * v1.z + a4.z * v2.z + a4.w * v3.z;
            accA.w += a4.x * v0.w + a4.y * v1.w + a4.z * v2.w + a4.w * v3.w;
            accC.x += c4.x * v0.x + c4.y * v1.x + c4.z * v2.x + c4.w * v3.x;
            accC.y += c4.x * v0.y + c4.y * v1.y + c4.z * v2.y + c4.w * v3.y;
            accC.z += c4.x * v0.z + c4.y * v1.z + c4.z * v2.z + c4.w * v3.z;
            accC.w += c4.x * v0.w + c4.y * v1.w + c4.z * v2.w + c4.w * v3.w;
        }
        float* gr = &g8p[half][r * 132 + 2 + 4 * cg];
        gr[0] = accA.x; gr[1] = accA.y; gr[2] = accA.z; gr[3] = accA.w;
        float* gr2 = gr + 66;
        gr2[0] = accC.x; gr2[1] = accC.y; gr2[2] = accC.z; gr2[3] = accC.w;
    }
    __syncthreads();
    for (int idx = tid; idx < 528; idx += 256) {
        int p = idx % 132;
        if ((p >= 2 && p < 66) || p >= 68) g8[idx] = g8p[0][idx] + g8p[1][idx];
    }
    __syncthreads();
    {   // gate: c=tid&127, rq=tid>>7 (0..1) -> rows rq*2+{0,1}
        int c = tid & 127, rq = tid >> 7;
        int r0 = rq * 2, r1 = r0 + 1;
        float bv = bru[c];
        float a0 = bv, a1 = bv;
        #pragma unroll
        for (int k = 0; k < 2; ++k) {
            float wv = Wru[k * 128 + c];
            a0 += xts[r0 * 2 + k] * wv;
            a1 += xts[r1 * 2 + k] * wv;
        }
        #pragma unroll 4
        for (int kg = 0; kg < 16; ++kg) {
            float4 f0 = *(const float4*)&sF[(i0 + r0) * 64 + 4 * kg];
            float4 f1 = *(const float4*)&sF[(i0 + r1) * 64 + 4 * kg];
            const float* Wp = Wru + (2 + 4 * kg) * 128 + c;
            float w0 = Wp[0], w1 = Wp[128], w2 = Wp[256], w3 = Wp[384];
            a0 += f0.x * w0 + f0.y * w1 + f0.z * w2 + f0.w * w3;
            a1 += f1.x * w0 + f1.y * w1 + f1.z * w2 + f1.w * w3;
        }
        #pragma unroll 4
        for (int kg = 0; kg < 33; ++kg) {
            float4 f0 = *(const float4*)&g8[r0 * 132 + 4 * kg];
            float4 f1 = *(const float4*)&g8[r1 * 132 + 4 * kg];
            const float* Wp = Wru + (66 + 4 * kg) * 128 + c;
            float w0 = Wp[0], w1 = Wp[128], w2 = Wp[256], w3 = Wp[384];
            a0 += f0.x * w0 + f0.y * w1 + f0.z * w2 + f0.w * w3;
            a1 += f1.x * w0 + f1.y * w1 + f1.z * w2 + f1.w * w3;
        }
        float v0 = sigm(a0), v1 = sigm(a1);
        size_t gr0 = (size_t)b * N_ + i0 + r0, gr1 = gr0 + 1;
        if (c < 64) {
            rs[gr0 * 64 + c] = v0 * sF[(i0 + r0) * 64 + c];
            rs[gr1 * 64 + c] = v1 * sF[(i0 + r1) * 64 + c];
        } else {
            ub[gr0 * 64 + (c - 64)] = v0;
            ub[gr1 * 64 + (c - 64)] = v1;
        }
    }
}

// ======== K2: hops + cand gate + state update (4 rows/block) ========
__global__ void __launch_bounds__(256) k_cand2(
        const float* __restrict__ At, const float* __restrict__ A2t,
        const float* __restrict__ xht,
        const float* __restrict__ x, int t, const float* __restrict__ rsin,
        const float* __restrict__ Wcd, const float* __restrict__ bcd,
        const float* __restrict__ ub, float* __restrict__ state) {
    __shared__ float sF[200 * 64];
    __shared__ float a4s[4 * 200], c4s[4 * 200];
    __shared__ float g8[4 * 132];
    __shared__ float g8p[2][4 * 132];
    __shared__ float xts[8];
    int bx = blockIdx.x;
    int b = bx & 7, i0 = (bx >> 3) * 4;      // XCD-local batches
    int tid = threadIdx.x;
    {
        const float4* rbv = (const float4*)(rsin + (size_t)b * N_ * 64);
        float4* sFv = (float4*)sF;
        for (int idx = tid; idx < 3200; idx += 256) sFv[idx] = rbv[idx];
        const float4* Ar = (const float4*)(At + ((size_t)b * N_ + i0) * 200);
        const float4* Cr = (const float4*)(A2t + ((size_t)b * N_ + i0) * 200);
        float4* av = (float4*)a4s; float4* cv = (float4*)c4s;
        for (int idx = tid; idx < 200; idx += 256) { av[idx] = Ar[idx]; cv[idx] = Cr[idx]; }
        if (tid < 8) xts[tid] = x[((size_t)(b * T_ + t) * N_ + i0 + (tid >> 1)) * 2 + (tid & 1)];
        if (tid >= 8 && tid < 24) {
            int l = tid - 8, rr = l >> 2, q = l & 3;
            g8[rr * 132 + ((q < 2) ? q : q + 64)] = xht[((size_t)b * N_ + i0 + rr) * 4 + q];
        }
    }
    __syncthreads();
    if (tid < 128) {   // hop: 2 waves, each 25 jg, both matrices
        int half = tid >> 6;
        int r = (tid >> 4) & 3, cg = tid & 15;
        const float* ar = a4s + r * 200 + half * 100;
        const float* cr = c4s + r * 200 + half * 100;
        const float* fbase = &sF[half * 100 * 64];
        float4 accA = make_float4(0.f, 0.f, 0.f, 0.f);
        float4 accC = make_float4(0.f, 0.f, 0.f, 0.f);
        #pragma unroll 5
        for (int jg = 0; jg < 25; ++jg) {
            float4 a4 = *(const float4*)&ar[4 * jg];
            float4 c4 = *(const float4*)&cr[4 * jg];
            const float* fb = fbase + (4 * jg) * 64 + 4 * cg;
            float4 v0 = *(const float4*)fb;
            float4 v1 = *(const float4*)(fb + 64);
            float4 v2 = *(const float4*)(fb + 128);
            float4 v3 = *(const float4*)(fb + 192);
            accA.x += a4.x * v0.x + a4.y * v1.x + a4.z * v2.x + a4.w * v3.x;
            accA.y += a4.x * v0.y + a4.y * v1.y + a4.z * v2.y + a4.w * v3.y;
            accA.z += a4.x * v0.z + a4.y * v1.z + a4.z * v2.z + a4.w * v3.z;
            accA.w += a4.x * v0.w + a4.y * v1.w + a4.z * v2.w + a4.w * v3.w;
            accC.x += c4.x * v0.x + c4.y * v1.x + c4.z * v2.x + c4.w * v3.x;
            accC.y += c4.x * v0.y + c4.y * v1.y + c4.z * v2.y + c4.w * v3.y;
            accC.z += c4.x * v0.z + c4.y * v1.z + c4.z * v2.z + c4.w * v3.z;
            accC.w += c4.x * v0.w + c4.y * v1.w + c4.z * v2.w + c4.w * v3.w;
        }
        float* gr = &g8p[half][r * 132 + 2 + 4 * cg];
        gr[0] = accA.x; gr[1] = accA.y; gr[2] = accA.z; gr[3] = accA.w;
        float* gr2 = gr + 66;
        gr2[0] = accC.x; gr2[1] = accC.y; gr2[2] = accC.z; gr2[3] = accC.w;
    }
    __syncthreads();
    for (int idx = tid; idx < 528; idx += 256) {
        int p = idx % 132;
        if ((p >= 2 && p < 66) || p >= 68) g8[idx] = g8p[0][idx] + g8p[1][idx];
    }
    __syncthreads();
    {   // gate: r=tid>>6 (0..3), c=tid&63 — one output each
        int c = tid & 63, r = tid >> 6;
        float a0 = bcd[c];
        #pragma unroll
        for (int k = 0; k < 2; ++k) a0 += xts[r * 2 + k] * Wcd[k * 64 + c];
        #pragma unroll 4
        for (int kg = 0; kg < 16; ++kg) {
            float4 f0 = *(const float4*)&sF[(i0 + r) * 64 + 4 * kg];
            const float* Wp = Wcd + (2 + 4 * kg) * 64 + c;
            a0 += f0.x * Wp[0] + f0.y * Wp[64] + f0.z * Wp[128] + f0.w * Wp[192];
        }
        #pragma unroll 4
        for (int kg = 0; kg < 33; ++kg) {
            float4 f0 = *(const float4*)&g8[r * 132 + 4 * kg];
            const float* Wp = Wcd + (66 + 4 * kg) * 64 + c;
            a0 += f0.x * Wp[0] + f0.y * Wp[64] + f0.z * Wp[128] + f0.w * Wp[192];
        }
        size_t gr = (size_t)b * N_ + i0 + r;
        float cnd = tanhf(a0);
        float u = ub[gr * 64 + c];
        float st = state[gr * 64 + c];
        state[gr * 64 + c] = u * st + (1.f - u) * cnd;
    }
}

// ======== pred head ========
__global__ void __launch_bounds__(64) k_pred(
        const float* __restrict__ state,
        const float* __restrict__ Wp1, const float* __restrict__ bp1,
        const float* __restrict__ Wp2, const float* __restrict__ bp2,
        float* __restrict__ out) {
    __shared__ float st[64];
    int row = blockIdx.x;
    int tid = threadIdx.x;
    st[tid] = state[row * 64 + tid];
    __syncthreads();
    float acc = bp1[tid];
    #pragma unroll 8
    for (int a = 0; a < 64; ++a) acc += st[a] * Wp1[a * 64 + tid];
    acc = acc > 0.f ? acc : 0.01f * acc;
    float v = acc * Wp2[tid];
    #pragma unroll
    for (int off = 32; off > 0; off >>= 1) v += __shfl_down(v, off);
    if (tid == 0) out[row] = v + bp2[0];
}

extern "C" void kernel_launch(void* const* d_in, const int* in_sizes, int n_in,
                              void* d_out, int out_size, void* d_ws, size_t ws_size,
                              hipStream_t stream) {
    const float* x    = (const float*)d_in[0];
    const float* nf   = (const float*)d_in[1];
    const float* Ws2d = (const float*)d_in[2];
    const float* bs2d = (const float*)d_in[3];
    const float* Wrz  = (const float*)d_in[4];
    const float* brz  = (const float*)d_in[5];
    const float* Wh   = (const float*)d_in[6];
    const float* bh   = (const float*)d_in[7];
    const float* Wc2  = (const float*)d_in[8];
    const float* bc2  = (const float*)d_in[9];
    const float* Wc1  = (const float*)d_in[10];
    const float* bc1  = (const float*)d_in[11];
    const float* Wm2  = (const float*)d_in[12];
    const float* bm2  = (const float*)d_in[13];
    const float* Wm1  = (const float*)d_in[14];
    const float* bm1  = (const float*)d_in[15];
    const float* Wru  = (const float*)d_in[16];
    const float* bru  = (const float*)d_in[17];
    const float* Wcand= (const float*)d_in[18];
    const float* bcand= (const float*)d_in[19];
    const float* Wp1  = (const float*)d_in[20];
    const float* bp1  = (const float*)d_in[21];
    const float* Wp2  = (const float*)d_in[22];
    const float* bp2  = (const float*)d_in[23];
    float* out = (float*)d_out;

    float* ws = (float*)d_ws;
    const size_t PQ = (size_t)T_ * R_ * 32;
    float* Pc = ws;
    float* Qc = Pc + PQ;
    float* Pm = Qc + PQ;
    float* Qm = Pm + PQ;

    const size_t A2F = (size_t)96 * NN_;
    const size_t XHF = (size_t)96 * N_ * 4;
    const size_t FULL_NEED = (A2F + XHF + 3 * (size_t)R_ * 64) * 4;
    bool full = ws_size >= FULL_NEED;

    const float* Aall = out + R_;

    if (full) {
        float* A2base = ws;                  // aliases dead P/Q after k_pairall
        float* xhbase = ws + A2F;
        float* state  = xhbase + XHF;
        float* rs     = state + (size_t)R_ * 64;
        float* ub     = rs + (size_t)R_ * 64;

        k_dyall<<<400, 256, 0, stream>>>(x, nf, Ws2d, bs2d, Wrz, brz, Wh, bh,
                                         Wc2, Wm2, bc2, bm2, Pc, Qc, Pm, Qm, state);
        k_pairall<<<dim3(7, 13, 96), dim3(16, 16), 0, stream>>>(
            Pc, Qc, Pm, Qm, Wc1, bc1, Wm1, bm1, out);
        k_a2<<<96 * 8, 128, 0, stream>>>(Aall, A2base, 96);
        k_xh<<<96, 256, 0, stream>>>(Aall, A2base, x, 0, xhbase);

        for (int t = 0; t < T_; ++t) {
            const float* At  = Aall + (size_t)t * 8 * NN_;
            const float* A2t = A2base + (size_t)t * 8 * NN_;
            const float* xht = xhbase + (size_t)t * 8 * N_ * 4;
            k_ru2  <<<400, 256, 0, stream>>>(At, A2t, xht, x, t, state, Wru, bru, rs, ub);
            k_cand2<<<400, 256, 0, stream>>>(At, A2t, xht, x, t, rs, Wcand, bcand, ub, state);
        }
        k_pred<<<R_, 64, 0, stream>>>(state, Wp1, bp1, Wp2, bp2, out);
    } else {
        float* A2base = ws + 4 * PQ;
        float* xhbase = A2base + (size_t)8 * NN_;
        float* state  = xhbase + (size_t)8 * N_ * 4;
        float* rs     = state + (size_t)R_ * 64;
        float* ub     = rs + (size_t)R_ * 64;

        k_dyall<<<400, 256, 0, stream>>>(x, nf, Ws2d, bs2d, Wrz, brz, Wh, bh,
                                         Wc2, Wm2, bc2, bm2, Pc, Qc, Pm, Qm, state);
        k_pairall<<<dim3(7, 13, 96), dim3(16, 16), 0, stream>>>(
            Pc, Qc, Pm, Qm, Wc1, bc1, Wm1, bm1, out);
        for (int t = 0; t < T_; ++t) {
            const float* At = Aall + (size_t)t * 8 * NN_;
            k_a2<<<8 * 8, 128, 0, stream>>>(At, A2base, 8);
            k_xh<<<8, 256, 0, stream>>>(At, A2base, x, t * 8, xhbase);
            k_ru2  <<<400, 256, 0, stream>>>(At, A2base, xhbase, x, t, state, Wru, bru, rs, ub);
            k_cand2<<<400, 256, 0, stream>>>(At, A2base, xhbase, x, t, rs, Wcand, bcand, ub, state);
        }
        k_pred<<<R_, 64, 0, stream>>>(state, Wp1, bp1, Wp2, bp2, out);
    }
}

// Round 5
// 550.805 us; speedup vs baseline: 1.0717x; 1.0717x over previous
//
#include <hip/hip_runtime.h>
#include <math.h>

#define B_ 8
#define T_ 12
#define N_ 200
#define R_ 1600    // B*N
#define NN_ 40000  // N*N

__device__ __forceinline__ float sigm(float v) { return 1.f / (1.f + expf(-v)); }

// ======== Phase A: dy-GRU chain + P/Q projections (bias folded into P) ====
__global__ void __launch_bounds__(256) k_dyall(
        const float* __restrict__ x,  const float* __restrict__ nf,
        const float* __restrict__ Ws2d, const float* __restrict__ bs2d,
        const float* __restrict__ Wrz,  const float* __restrict__ brz,
        const float* __restrict__ Wh,   const float* __restrict__ bh,
        const float* __restrict__ Wc2,  const float* __restrict__ Wm2,
        const float* __restrict__ bc2,  const float* __restrict__ bm2,
        float* __restrict__ Pc, float* __restrict__ Qc,
        float* __restrict__ Pm, float* __restrict__ Qm,
        float* __restrict__ state) {
    __shared__ float sWs2d[64 * 32], sWrz[33 * 64], sWh[33 * 32];
    __shared__ float sWc2[64 * 32], sWm2[64 * 32];
    __shared__ float sbrz[64], sbh[32], sbs2d[32], sbc2[32], sbm2[32];
    __shared__ float nfs[4][64], dy[4][32], in1[4][33], in2[4][33], rz[4][64], s4[4][32];
    int bk = blockIdx.x, tid = threadIdx.x;
    int w = tid >> 6, o = tid & 63;
    int row = bk * 4 + w, b = row / N_, n = row % N_;
    state[bk * 256 + tid] = 0.f;
    for (int idx = tid; idx < 2048; idx += 256) sWs2d[idx] = Ws2d[idx];
    for (int idx = tid; idx < 2112; idx += 256) sWrz[idx] = Wrz[idx];
    for (int idx = tid; idx < 1056; idx += 256) sWh[idx] = Wh[idx];
    for (int idx = tid; idx < 2048; idx += 256) { sWc2[idx] = Wc2[idx]; sWm2[idx] = Wm2[idx]; }
    if (tid < 64) sbrz[tid] = brz[tid];
    if (tid < 32) { sbh[tid] = bh[tid]; sbs2d[tid] = bs2d[tid];
                    sbc2[tid] = bc2[tid]; sbm2[tid] = bm2[tid]; }
    nfs[w][o] = nf[n * 64 + o];
    __syncthreads();
    if (o < 32) {
        float acc = sbs2d[o];
        #pragma unroll 8
        for (int i = 0; i < 64; ++i) acc += nfs[w][i] * sWs2d[i * 32 + o];
        dy[w][o] = acc;
    }
    __syncthreads();
    for (int t = 0; t < T_; ++t) {
        if (o == 0) { float v = x[((b * T_ + t) * N_ + n) * 2]; in1[w][0] = v; in2[w][0] = v; }
        if (o < 32) in1[w][o + 1] = dy[w][o];
        __syncthreads();
        float acc = sbrz[o];
        #pragma unroll
        for (int i = 0; i < 33; ++i) acc += in1[w][i] * sWrz[i * 64 + o];
        rz[w][o] = sigm(acc);
        __syncthreads();
        if (o < 32) in2[w][o + 1] = rz[w][o] * dy[w][o];
        __syncthreads();
        if (o < 32) {
            float h = sbh[o];
            #pragma unroll
            for (int i = 0; i < 33; ++i) h += in2[w][i] * sWh[i * 32 + o];
            h = tanhf(h);
            float z = rz[w][32 + o];
            float nd = z * dy[w][o] + (1.f - z) * h;
            dy[w][o] = nd;
            s4[w][o] = nd > 0.f ? nd : 0.f;
        }
        __syncthreads();
        size_t base = ((size_t)t * R_ + row) * 32;
        for (int idx = o; idx < 128; idx += 64) {
            int mat = idx >> 5, k = idx & 31;
            const float* W = (mat < 2) ? sWc2 : sWm2;
            int rb = (mat & 1) ? 32 : 0;
            float a = (mat == 0) ? sbc2[k] : (mat == 2) ? sbm2[k] : 0.f;
            #pragma unroll
            for (int i = 0; i < 32; ++i) a += s4[w][i] * W[(rb + i) * 32 + k];
            ((mat == 0) ? Pc : (mat == 1) ? Qc : (mat == 2) ? Pm : Qm)[base + k] = a;
        }
        __syncthreads();
    }
}

// ======== Phase B: adjacency matrices — R1-proven 16x16 version ====
__global__ void __launch_bounds__(256) k_pairall(
        const float* __restrict__ Pc, const float* __restrict__ Qc,
        const float* __restrict__ Pm, const float* __restrict__ Qm,
        const float* __restrict__ Wc1, const float* __restrict__ bc1,
        const float* __restrict__ Wm1, const float* __restrict__ bm1,
        float* __restrict__ out) {
    __shared__ float sPc[16][36], sQc[16][36], sPm[16][36], sQm[16][36];
    __shared__ float sWc1[32], sWm1[32];
    int z = blockIdx.z;            // t*8 + b
    int i0 = blockIdx.x * 16, j0 = blockIdx.y * 16;
    int tid = threadIdx.y * 16 + threadIdx.x;
    size_t tb = (size_t)z * N_;
    for (int l = tid; l < 128; l += 256) {   // 16 rows x 8 float4
        int r = l >> 3, q = l & 7;
        int gi = i0 + r, gj = j0 + r;
        float4 z4 = make_float4(0.f, 0.f, 0.f, 0.f);
        *(float4*)&sPc[r][4 * q] = (gi < N_) ? *(const float4*)&Pc[(tb + gi) * 32 + 4 * q] : z4;
        *(float4*)&sPm[r][4 * q] = (gi < N_) ? *(const float4*)&Pm[(tb + gi) * 32 + 4 * q] : z4;
        *(float4*)&sQc[r][4 * q] = (gj < N_) ? *(const float4*)&Qc[(tb + gj) * 32 + 4 * q] : z4;
        *(float4*)&sQm[r][4 * q] = (gj < N_) ? *(const float4*)&Qm[(tb + gj) * 32 + 4 * q] : z4;
    }
    if (tid < 32) { sWc1[tid] = Wc1[tid]; sWm1[tid] = Wm1[tid]; }
    __syncthreads();
    int i = i0 + threadIdx.y, j = j0 + threadIdx.x;
    if (i >= N_ || j >= N_) return;
    int ty = threadIdx.y, tx = threadIdx.x;
    float g0 = 0.f, g1 = 0.f, m0 = 0.f, m1 = 0.f;
    #pragma unroll
    for (int kg = 0; kg < 8; ++kg) {
        float4 pc = *(const float4*)&sPc[ty][4 * kg];
        float4 qc = *(const float4*)&sQc[tx][4 * kg];
        float4 wc = *(const float4*)&sWc1[4 * kg];
        g0 += fmaxf(pc.x + qc.x, 0.f) * wc.x + fmaxf(pc.y + qc.y, 0.f) * wc.y;
        g1 += fmaxf(pc.z + qc.z, 0.f) * wc.z + fmaxf(pc.w + qc.w, 0.f) * wc.w;
        float4 pm = *(const float4*)&sPm[ty][4 * kg];
        float4 qm = *(const float4*)&sQm[tx][4 * kg];
        float4 wm = *(const float4*)&sWm1[4 * kg];
        m0 += fmaxf(pm.x + qm.x, 0.f) * wm.x + fmaxf(pm.y + qm.y, 0.f) * wm.y;
        m1 += fmaxf(pm.z + qm.z, 0.f) * wm.z + fmaxf(pm.w + qm.w, 0.f) * wm.w;
    }
    float g = g0 + g1 + bc1[0];
    float m = m0 + m1 + bm1[0];
    out[R_ + (((size_t)z * N_ + i) * N_ + j)] = g * sigm(m);
}

// ======== A2 = A @ A — R1-proven: 128x64 tile, 256 thr, 8x4 micro, BK=32 ==
__global__ void __launch_bounds__(256) k_a2(
        const float* __restrict__ Abase, float* __restrict__ Cbase, int nmat) {
    __shared__ float Ast[32][132];   // [k][i] transposed
    __shared__ float Bs[32][68];     // [k][j]
    int bx = blockIdx.x;
    int z = bx % nmat, tl = bx / nmat;      // z fastest => XCD-local matrices
    int i0 = (tl >> 2) * 128, j0 = (tl & 3) * 64;
    const float* Az = Abase + (size_t)z * NN_;
    float* Cz = Cbase + (size_t)z * NN_;
    int tid = threadIdx.x;
    int tx = tid & 15, ty = tid >> 4;       // tx: 4-col group, ty: 8-row group
    float acc[8][4] = {};
    for (int k0 = 0; k0 < 200; k0 += 32) {
        {
            int i = tid >> 1;                 // 0..127
            int kb = (tid & 1) * 16;          // 0 or 16
            int gi = i0 + i;
            #pragma unroll
            for (int q = 0; q < 4; ++q) {
                int k = kb + q * 4;
                int gk = k0 + k;
                float4 v = make_float4(0.f, 0.f, 0.f, 0.f);
                if (gi < N_) {
                    if (gk + 3 < N_) v = *(const float4*)&Az[gi * N_ + gk];
                    else {
                        float t0 = (gk + 0 < N_) ? Az[gi * N_ + gk + 0] : 0.f;
                        float t1 = (gk + 1 < N_) ? Az[gi * N_ + gk + 1] : 0.f;
                        float t2 = (gk + 2 < N_) ? Az[gi * N_ + gk + 2] : 0.f;
                        float t3 = (gk + 3 < N_) ? Az[gi * N_ + gk + 3] : 0.f;
                        v = make_float4(t0, t1, t2, t3);
                    }
                }
                Ast[k + 0][i] = v.x; Ast[k + 1][i] = v.y;
                Ast[k + 2][i] = v.z; Ast[k + 3][i] = v.w;
            }
        }
        {
            #pragma unroll
            for (int q = 0; q < 2; ++q) {
                int id = tid + 256 * q;       // 0..511
                int k = id >> 4, jq = (id & 15) * 4;
                int gk = k0 + k, gj = j0 + jq;
                float4 v = make_float4(0.f, 0.f, 0.f, 0.f);
                if (gk < N_) {
                    if (gj + 3 < N_) v = *(const float4*)&Az[gk * N_ + gj];
                    else {
                        float t0 = (gj + 0 < N_) ? Az[gk * N_ + gj + 0] : 0.f;
                        float t1 = (gj + 1 < N_) ? Az[gk * N_ + gj + 1] : 0.f;
                        float t2 = (gj + 2 < N_) ? Az[gk * N_ + gj + 2] : 0.f;
                        float t3 = (gj + 3 < N_) ? Az[gk * N_ + gj + 3] : 0.f;
                        v = make_float4(t0, t1, t2, t3);
                    }
                }
                *(float4*)&Bs[k][jq] = v;
            }
        }
        __syncthreads();
        #pragma unroll 8
        for (int k = 0; k < 32; ++k) {
            float4 a0 = *(const float4*)&Ast[k][ty * 8];
            float4 a1 = *(const float4*)&Ast[k][ty * 8 + 4];
            float4 bv = *(const float4*)&Bs[k][tx * 4];
            acc[0][0] += a0.x * bv.x; acc[0][1] += a0.x * bv.y; acc[0][2] += a0.x * bv.z; acc[0][3] += a0.x * bv.w;
            acc[1][0] += a0.y * bv.x; acc[1][1] += a0.y * bv.y; acc[1][2] += a0.y * bv.z; acc[1][3] += a0.y * bv.w;
            acc[2][0] += a0.z * bv.x; acc[2][1] += a0.z * bv.y; acc[2][2] += a0.z * bv.z; acc[2][3] += a0.z * bv.w;
            acc[3][0] += a0.w * bv.x; acc[3][1] += a0.w * bv.y; acc[3][2] += a0.w * bv.z; acc[3][3] += a0.w * bv.w;
            acc[4][0] += a1.x * bv.x; acc[4][1] += a1.x * bv.y; acc[4][2] += a1.x * bv.z; acc[4][3] += a1.x * bv.w;
            acc[5][0] += a1.y * bv.x; acc[5][1] += a1.y * bv.y; acc[5][2] += a1.y * bv.z; acc[5][3] += a1.y * bv.w;
            acc[6][0] += a1.z * bv.x; acc[6][1] += a1.z * bv.y; acc[6][2] += a1.z * bv.z; acc[6][3] += a1.z * bv.w;
            acc[7][0] += a1.w * bv.x; acc[7][1] += a1.w * bv.y; acc[7][2] += a1.w * bv.z; acc[7][3] += a1.w * bv.w;
        }
        __syncthreads();
    }
    #pragma unroll
    for (int r = 0; r < 8; ++r) {
        int gi = i0 + ty * 8 + r;
        if (gi >= N_) continue;
        int gj = j0 + tx * 4;
        if (gj + 3 < N_) {
            *(float4*)&Cz[gi * N_ + gj] = make_float4(acc[r][0], acc[r][1], acc[r][2], acc[r][3]);
        } else {
            #pragma unroll
            for (int e = 0; e < 4; ++e) if (gj + e < N_) Cz[gi * N_ + gj + e] = acc[r][e];
        }
    }
}

// ======== xt-hops: xh[zl][i][4] = {A@x0, A@x1, A2@x0, A2@x1} ========
__global__ void __launch_bounds__(256) k_xh(
        const float* __restrict__ Abase, const float* __restrict__ A2base,
        const float* __restrict__ x, int z0, float* __restrict__ xh) {
    __shared__ float xtl[400];
    int zl = blockIdx.x, tid = threadIdx.x;
    int z = z0 + zl, t = z >> 3, b = z & 7;
    int w = tid >> 6, l = tid & 63;
    const float* xb = x + ((size_t)(b * T_ + t)) * N_ * 2;
    for (int idx = tid; idx < 400; idx += 256) xtl[idx] = xb[idx];
    __syncthreads();
    for (int it = 0; it < 50; ++it) {
        int i = it * 4 + w;
        float p0 = 0.f, p1 = 0.f, p2 = 0.f, p3 = 0.f;
        if (l < 50) {
            float4 a4 = *(const float4*)(Abase + (size_t)zl * NN_ + i * 200 + 4 * l);
            float4 c4 = *(const float4*)(A2base + (size_t)zl * NN_ + i * 200 + 4 * l);
            #pragma unroll
            for (int q = 0; q < 4; ++q) {
                float av = (&a4.x)[q], cv = (&c4.x)[q];
                float x0 = xtl[(4 * l + q) * 2], x1 = xtl[(4 * l + q) * 2 + 1];
                p0 += av * x0; p1 += av * x1; p2 += cv * x0; p3 += cv * x1;
            }
        }
        #pragma unroll
        for (int off = 32; off > 0; off >>= 1) {
            p0 += __shfl_down(p0, off); p1 += __shfl_down(p1, off);
            p2 += __shfl_down(p2, off); p3 += __shfl_down(p3, off);
        }
        if (l == 0) *(float4*)(xh + ((size_t)zl * N_ + i) * 4) = make_float4(p0, p1, p2, p3);
    }
}

// ======== K1: 2 rows/block, 800 blocks, NO sF staging (F read from L2) ====
// Hop uses all 4 waves: wave = (h<<1)|r, lanes = 16 col-groups x 4 j-strides;
// shfl_xor(16,32) reduces j-strides in-register; LDS combines halves.
// LDS ~7KB (vs 64KB) -> latency hidden by 3 blocks/CU instead of barriers.
__global__ void __launch_bounds__(256) k_ru2(
        const float* __restrict__ At, const float* __restrict__ A2t,
        const float* __restrict__ xht,
        const float* __restrict__ x, int t, const float* __restrict__ state,
        const float* __restrict__ Wru, const float* __restrict__ bru,
        float* __restrict__ rs, float* __restrict__ ub) {
    __shared__ float a2s[2 * 200], c2s[2 * 200];
    __shared__ float hpA[4][64], hpC[4][64];
    __shared__ float g8[2][132];
    __shared__ float xts[4];
    int bx = blockIdx.x;
    int b = bx & 7, i0 = (bx >> 3) * 2;      // b == XCD -> state stays L2-local
    int tid = threadIdx.x;
    const float* F = state + (size_t)b * (N_ * 64);
    {
        const float4* Ar = (const float4*)(At + ((size_t)b * N_ + i0) * 200);
        const float4* Cr = (const float4*)(A2t + ((size_t)b * N_ + i0) * 200);
        if (tid < 100) { ((float4*)a2s)[tid] = Ar[tid]; ((float4*)c2s)[tid] = Cr[tid]; }
        if (tid >= 128 && tid < 132) {
            int l = tid - 128;
            xts[l] = x[((size_t)(b * T_ + t) * N_ + i0 + (l >> 1)) * 2 + (l & 1)];
        }
        if (tid >= 136 && tid < 144) {
            int l = tid - 136, rr = l >> 2, q = l & 3;
            g8[rr][(q < 2) ? q : q + 64] = xht[((size_t)b * N_ + i0 + rr) * 4 + q];
        }
    }
    __syncthreads();
    {   // hop
        int w = tid >> 6, lane = tid & 63;
        int r = w & 1, h = w >> 1;
        int cg = lane & 15, jq = lane >> 4;
        const float* ar = a2s + r * 200 + h * 100;
        const float* cr = c2s + r * 200 + h * 100;
        const float* Fb = F + (size_t)(h * 100) * 64 + 4 * cg;
        float4 accA = make_float4(0.f, 0.f, 0.f, 0.f);
        float4 accC = make_float4(0.f, 0.f, 0.f, 0.f);
        #pragma unroll 5
        for (int m = 0; m < 25; ++m) {
            int j = jq + 4 * m;
            float av = ar[j], cv = cr[j];
            float4 f4 = *(const float4*)&Fb[(size_t)j * 64];
            accA.x += av * f4.x; accA.y += av * f4.y; accA.z += av * f4.z; accA.w += av * f4.w;
            accC.x += cv * f4.x; accC.y += cv * f4.y; accC.z += cv * f4.z; accC.w += cv * f4.w;
        }
        accA.x += __shfl_xor(accA.x, 16); accA.y += __shfl_xor(accA.y, 16);
        accA.z += __shfl_xor(accA.z, 16); accA.w += __shfl_xor(accA.w, 16);
        accC.x += __shfl_xor(accC.x, 16); accC.y += __shfl_xor(accC.y, 16);
        accC.z += __shfl_xor(accC.z, 16); accC.w += __shfl_xor(accC.w, 16);
        accA.x += __shfl_xor(accA.x, 32); accA.y += __shfl_xor(accA.y, 32);
        accA.z += __shfl_xor(accA.z, 32); accA.w += __shfl_xor(accA.w, 32);
        accC.x += __shfl_xor(accC.x, 32); accC.y += __shfl_xor(accC.y, 32);
        accC.z += __shfl_xor(accC.z, 32); accC.w += __shfl_xor(accC.w, 32);
        if (lane < 16) {
            *(float4*)&hpA[w][4 * cg] = accA;
            *(float4*)&hpC[w][4 * cg] = accC;
        }
    }
    __syncthreads();
    {   // combine halves -> g8 (layout: [xhA(0,1) hopA(2..65) xhC(66,67) hopC(68..131)])
        int mt = tid >> 7, r = (tid >> 6) & 1, c = tid & 63;
        float v = mt ? (hpC[r][c] + hpC[2 + r][c]) : (hpA[r][c] + hpA[2 + r][c]);
        g8[r][(mt ? 68 : 2) + c] = v;
    }
    __syncthreads();
    {   // gate: rq = row, c = output col (0..127)
        int rq = tid >> 7, c = tid & 127;
        int grow = i0 + rq;
        const float* Fr = F + (size_t)grow * 64;
        float a0 = bru[c] + xts[rq * 2 + 0] * Wru[c] + xts[rq * 2 + 1] * Wru[128 + c];
        #pragma unroll 4
        for (int kg = 0; kg < 16; ++kg) {
            float4 f0 = *(const float4*)&Fr[4 * kg];
            const float* Wp = Wru + (size_t)(2 + 4 * kg) * 128 + c;
            a0 += f0.x * Wp[0] + f0.y * Wp[128] + f0.z * Wp[256] + f0.w * Wp[384];
        }
        #pragma unroll 4
        for (int kg = 0; kg < 33; ++kg) {
            float4 f0 = *(const float4*)&g8[rq][4 * kg];
            const float* Wp = Wru + (size_t)(66 + 4 * kg) * 128 + c;
            a0 += f0.x * Wp[0] + f0.y * Wp[128] + f0.z * Wp[256] + f0.w * Wp[384];
        }
        float v = sigm(a0);
        size_t go = (size_t)b * N_ + grow;
        if (c < 64) rs[go * 64 + c] = v * Fr[c];
        else        ub[go * 64 + (c - 64)] = v;
    }
}

// ======== K2: same structure; gate k-split so all 256 threads work ========
__global__ void __launch_bounds__(256) k_cand2(
        const float* __restrict__ At, const float* __restrict__ A2t,
        const float* __restrict__ xht,
        const float* __restrict__ x, int t, const float* __restrict__ rsin,
        const float* __restrict__ Wcd, const float* __restrict__ bcd,
        const float* __restrict__ ub, float* __restrict__ state) {
    __shared__ float a2s[2 * 200], c2s[2 * 200];
    __shared__ float hpA[4][64], hpC[4][64];
    __shared__ float g8[2][132];
    __shared__ float xts[4];
    __shared__ float gp[2][2][64];
    int bx = blockIdx.x;
    int b = bx & 7, i0 = (bx >> 3) * 2;
    int tid = threadIdx.x;
    const float* F = rsin + (size_t)b * (N_ * 64);
    {
        const float4* Ar = (const float4*)(At + ((size_t)b * N_ + i0) * 200);
        const float4* Cr = (const float4*)(A2t + ((size_t)b * N_ + i0) * 200);
        if (tid < 100) { ((float4*)a2s)[tid] = Ar[tid]; ((float4*)c2s)[tid] = Cr[tid]; }
        if (tid >= 128 && tid < 132) {
            int l = tid - 128;
            xts[l] = x[((size_t)(b * T_ + t) * N_ + i0 + (l >> 1)) * 2 + (l & 1)];
        }
        if (tid >= 136 && tid < 144) {
            int l = tid - 136, rr = l >> 2, q = l & 3;
            g8[rr][(q < 2) ? q : q + 64] = xht[((size_t)b * N_ + i0 + rr) * 4 + q];
        }
    }
    __syncthreads();
    {   // hop
        int w = tid >> 6, lane = tid & 63;
        int r = w & 1, h = w >> 1;
        int cg = lane & 15, jq = lane >> 4;
        const float* ar = a2s + r * 200 + h * 100;
        const float* cr = c2s + r * 200 + h * 100;
        const float* Fb = F + (size_t)(h * 100) * 64 + 4 * cg;
        float4 accA = make_float4(0.f, 0.f, 0.f, 0.f);
        float4 accC = make_float4(0.f, 0.f, 0.f, 0.f);
        #pragma unroll 5
        for (int m = 0; m < 25; ++m) {
            int j = jq + 4 * m;
            float av = ar[j], cv = cr[j];
            float4 f4 = *(const float4*)&Fb[(size_t)j * 64];
            accA.x += av * f4.x; accA.y += av * f4.y; accA.z += av * f4.z; accA.w += av * f4.w;
            accC.x += cv * f4.x; accC.y += cv * f4.y; accC.z += cv * f4.z; accC.w += cv * f4.w;
        }
        accA.x += __shfl_xor(accA.x, 16); accA.y += __shfl_xor(accA.y, 16);
        accA.z += __shfl_xor(accA.z, 16); accA.w += __shfl_xor(accA.w, 16);
        accC.x += __shfl_xor(accC.x, 16); accC.y += __shfl_xor(accC.y, 16);
        accC.z += __shfl_xor(accC.z, 16); accC.w += __shfl_xor(accC.w, 16);
        accA.x += __shfl_xor(accA.x, 32); accA.y += __shfl_xor(accA.y, 32);
        accA.z += __shfl_xor(accA.z, 32); accA.w += __shfl_xor(accA.w, 32);
        accC.x += __shfl_xor(accC.x, 32); accC.y += __shfl_xor(accC.y, 32);
        accC.z += __shfl_xor(accC.z, 32); accC.w += __shfl_xor(accC.w, 32);
        if (lane < 16) {
            *(float4*)&hpA[w][4 * cg] = accA;
            *(float4*)&hpC[w][4 * cg] = accC;
        }
    }
    __syncthreads();
    {
        int mt = tid >> 7, r = (tid >> 6) & 1, c = tid & 63;
        float v = mt ? (hpC[r][c] + hpC[2 + r][c]) : (hpA[r][c] + hpA[2 + r][c]);
        g8[r][(mt ? 68 : 2) + c] = v;
    }
    __syncthreads();
    {   // gate, k-split across kh
        int kh = tid >> 7, rq = (tid >> 6) & 1, c = tid & 63;
        int grow = i0 + rq;
        const float* Fr = F + (size_t)grow * 64;
        float a0 = 0.f;
        if (kh == 0) {
            a0 = bcd[c] + xts[rq * 2 + 0] * Wcd[c] + xts[rq * 2 + 1] * Wcd[64 + c];
            #pragma unroll 4
            for (int kg = 0; kg < 16; ++kg) {
                float4 f0 = *(const float4*)&Fr[4 * kg];
                const float* Wp = Wcd + (size_t)(2 + 4 * kg) * 64 + c;
                a0 += f0.x * Wp[0] + f0.y * Wp[64] + f0.z * Wp[128] + f0.w * Wp[192];
            }
            #pragma unroll 4
            for (int kg = 0; kg < 8; ++kg) {
                float4 f0 = *(const float4*)&g8[rq][4 * kg];
                const float* Wp = Wcd + (size_t)(66 + 4 * kg) * 64 + c;
                a0 += f0.x * Wp[0] + f0.y * Wp[64] + f0.z * Wp[128] + f0.w * Wp[192];
            }
        } else {
            #pragma unroll 5
            for (int kg = 8; kg < 33; ++kg) {
                float4 f0 = *(const float4*)&g8[rq][4 * kg];
                const float* Wp = Wcd + (size_t)(66 + 4 * kg) * 64 + c;
                a0 += f0.x * Wp[0] + f0.y * Wp[64] + f0.z * Wp[128] + f0.w * Wp[192];
            }
        }
        gp[kh][rq][c] = a0;
    }
    __syncthreads();
    if (tid < 128) {
        int rq = tid >> 6, c = tid & 63;
        size_t go = (size_t)b * N_ + i0 + rq;
        float a = gp[0][rq][c] + gp[1][rq][c];
        float cnd = tanhf(a);
        float u = ub[go * 64 + c];
        float st = state[go * 64 + c];
        state[go * 64 + c] = u * st + (1.f - u) * cnd;
    }
}

// ======== pred head ========
__global__ void __launch_bounds__(64) k_pred(
        const float* __restrict__ state,
        const float* __restrict__ Wp1, const float* __restrict__ bp1,
        const float* __restrict__ Wp2, const float* __restrict__ bp2,
        float* __restrict__ out) {
    __shared__ float st[64];
    int row = blockIdx.x;
    int tid = threadIdx.x;
    st[tid] = state[row * 64 + tid];
    __syncthreads();
    float acc = bp1[tid];
    #pragma unroll 8
    for (int a = 0; a < 64; ++a) acc += st[a] * Wp1[a * 64 + tid];
    acc = acc > 0.f ? acc : 0.01f * acc;
    float v = acc * Wp2[tid];
    #pragma unroll
    for (int off = 32; off > 0; off >>= 1) v += __shfl_down(v, off);
    if (tid == 0) out[row] = v + bp2[0];
}

extern "C" void kernel_launch(void* const* d_in, const int* in_sizes, int n_in,
                              void* d_out, int out_size, void* d_ws, size_t ws_size,
                              hipStream_t stream) {
    const float* x    = (const float*)d_in[0];
    const float* nf   = (const float*)d_in[1];
    const float* Ws2d = (const float*)d_in[2];
    const float* bs2d = (const float*)d_in[3];
    const float* Wrz  = (const float*)d_in[4];
    const float* brz  = (const float*)d_in[5];
    const float* Wh   = (const float*)d_in[6];
    const float* bh   = (const float*)d_in[7];
    const float* Wc2  = (const float*)d_in[8];
    const float* bc2  = (const float*)d_in[9];
    const float* Wc1  = (const float*)d_in[10];
    const float* bc1  = (const float*)d_in[11];
    const float* Wm2  = (const float*)d_in[12];
    const float* bm2  = (const float*)d_in[13];
    const float* Wm1  = (const float*)d_in[14];
    const float* bm1  = (const float*)d_in[15];
    const float* Wru  = (const float*)d_in[16];
    const float* bru  = (const float*)d_in[17];
    const float* Wcand= (const float*)d_in[18];
    const float* bcand= (const float*)d_in[19];
    const float* Wp1  = (const float*)d_in[20];
    const float* bp1  = (const float*)d_in[21];
    const float* Wp2  = (const float*)d_in[22];
    const float* bp2  = (const float*)d_in[23];
    float* out = (float*)d_out;

    float* ws = (float*)d_ws;
    const size_t PQ = (size_t)T_ * R_ * 32;
    float* Pc = ws;
    float* Qc = Pc + PQ;
    float* Pm = Qc + PQ;
    float* Qm = Pm + PQ;

    const size_t A2F = (size_t)96 * NN_;
    const size_t XHF = (size_t)96 * N_ * 4;
    const size_t FULL_NEED = (A2F + XHF + 3 * (size_t)R_ * 64) * 4;
    bool full = ws_size >= FULL_NEED;

    const float* Aall = out + R_;

    if (full) {
        float* A2base = ws;                  // aliases dead P/Q after k_pairall
        float* xhbase = ws + A2F;
        float* state  = xhbase + XHF;
        float* rs     = state + (size_t)R_ * 64;
        float* ub     = rs + (size_t)R_ * 64;

        k_dyall<<<400, 256, 0, stream>>>(x, nf, Ws2d, bs2d, Wrz, brz, Wh, bh,
                                         Wc2, Wm2, bc2, bm2, Pc, Qc, Pm, Qm, state);
        k_pairall<<<dim3(13, 13, 96), dim3(16, 16), 0, stream>>>(
            Pc, Qc, Pm, Qm, Wc1, bc1, Wm1, bm1, out);
        k_a2<<<96 * 8, 256, 0, stream>>>(Aall, A2base, 96);
        k_xh<<<96, 256, 0, stream>>>(Aall, A2base, x, 0, xhbase);

        for (int t = 0; t < T_; ++t) {
            const float* At  = Aall + (size_t)t * 8 * NN_;
            const float* A2t = A2base + (size_t)t * 8 * NN_;
            const float* xht = xhbase + (size_t)t * 8 * N_ * 4;
            k_ru2  <<<800, 256, 0, stream>>>(At, A2t, xht, x, t, state, Wru, bru, rs, ub);
            k_cand2<<<800, 256, 0, stream>>>(At, A2t, xht, x, t, rs, Wcand, bcand, ub, state);
        }
        k_pred<<<R_, 64, 0, stream>>>(state, Wp1, bp1, Wp2, bp2, out);
    } else {
        float* A2base = ws + 4 * PQ;
        float* xhbase = A2base + (size_t)8 * NN_;
        float* state  = xhbase + (size_t)8 * N_ * 4;
        float* rs     = state + (size_t)R_ * 64;
        float* ub     = rs + (size_t)R_ * 64;

        k_dyall<<<400, 256, 0, stream>>>(x, nf, Ws2d, bs2d, Wrz, brz, Wh, bh,
                                         Wc2, Wm2, bc2, bm2, Pc, Qc, Pm, Qm, state);
        k_pairall<<<dim3(13, 13, 96), dim3(16, 16), 0, stream>>>(
            Pc, Qc, Pm, Qm, Wc1, bc1, Wm1, bm1, out);
        for (int t = 0; t < T_; ++t) {
            const float* At = Aall + (size_t)t * 8 * NN_;
            k_a2<<<8 * 8, 256, 0, stream>>>(At, A2base, 8);
            k_xh<<<8, 256, 0, stream>>>(At, A2base, x, t * 8, xhbase);
            k_ru2  <<<800, 256, 0, stream>>>(At, A2base, xhbase, x, t, state, Wru, bru, rs, ub);
            k_cand2<<<800, 256, 0, stream>>>(At, A2base, xhbase, x, t, rs, Wcand, bcand, ub, state);
        }
        k_pred<<<R_, 64, 0, stream>>>(state, Wp1, bp1, Wp2, bp2, out);
    }
}

// Round 6
// 477.439 us; speedup vs baseline: 1.2364x; 1.1537x over previous
//
#include <hip/hip_runtime.h>
#include <math.h>

#define B_ 8
#define T_ 12
#define N_ 200
#define R_ 1600    // B*N
#define NN_ 40000  // N*N

__device__ __forceinline__ float sigm(float v) { return 1.f / (1.f + expf(-v)); }

// ======== Phase A: dy-GRU chain + P/Q projections (bias folded into P) ====
__global__ void __launch_bounds__(256) k_dyall(
        const float* __restrict__ x,  const float* __restrict__ nf,
        const float* __restrict__ Ws2d, const float* __restrict__ bs2d,
        const float* __restrict__ Wrz,  const float* __restrict__ brz,
        const float* __restrict__ Wh,   const float* __restrict__ bh,
        const float* __restrict__ Wc2,  const float* __restrict__ Wm2,
        const float* __restrict__ bc2,  const float* __restrict__ bm2,
        float* __restrict__ Pc, float* __restrict__ Qc,
        float* __restrict__ Pm, float* __restrict__ Qm,
        float* __restrict__ state) {
    __shared__ float sWs2d[64 * 32], sWrz[33 * 64], sWh[33 * 32];
    __shared__ float sWc2[64 * 32], sWm2[64 * 32];
    __shared__ float sbrz[64], sbh[32], sbs2d[32], sbc2[32], sbm2[32];
    __shared__ float nfs[4][64], dy[4][32], in1[4][33], in2[4][33], rz[4][64], s4[4][32];
    int bk = blockIdx.x, tid = threadIdx.x;
    int w = tid >> 6, o = tid & 63;
    int row = bk * 4 + w, b = row / N_, n = row % N_;
    state[bk * 256 + tid] = 0.f;
    for (int idx = tid; idx < 2048; idx += 256) sWs2d[idx] = Ws2d[idx];
    for (int idx = tid; idx < 2112; idx += 256) sWrz[idx] = Wrz[idx];
    for (int idx = tid; idx < 1056; idx += 256) sWh[idx] = Wh[idx];
    for (int idx = tid; idx < 2048; idx += 256) { sWc2[idx] = Wc2[idx]; sWm2[idx] = Wm2[idx]; }
    if (tid < 64) sbrz[tid] = brz[tid];
    if (tid < 32) { sbh[tid] = bh[tid]; sbs2d[tid] = bs2d[tid];
                    sbc2[tid] = bc2[tid]; sbm2[tid] = bm2[tid]; }
    nfs[w][o] = nf[n * 64 + o];
    __syncthreads();
    if (o < 32) {
        float acc = sbs2d[o];
        #pragma unroll 8
        for (int i = 0; i < 64; ++i) acc += nfs[w][i] * sWs2d[i * 32 + o];
        dy[w][o] = acc;
    }
    __syncthreads();
    for (int t = 0; t < T_; ++t) {
        if (o == 0) { float v = x[((b * T_ + t) * N_ + n) * 2]; in1[w][0] = v; in2[w][0] = v; }
        if (o < 32) in1[w][o + 1] = dy[w][o];
        __syncthreads();
        float acc = sbrz[o];
        #pragma unroll
        for (int i = 0; i < 33; ++i) acc += in1[w][i] * sWrz[i * 64 + o];
        rz[w][o] = sigm(acc);
        __syncthreads();
        if (o < 32) in2[w][o + 1] = rz[w][o] * dy[w][o];
        __syncthreads();
        if (o < 32) {
            float h = sbh[o];
            #pragma unroll
            for (int i = 0; i < 33; ++i) h += in2[w][i] * sWh[i * 32 + o];
            h = tanhf(h);
            float z = rz[w][32 + o];
            float nd = z * dy[w][o] + (1.f - z) * h;
            dy[w][o] = nd;
            s4[w][o] = nd > 0.f ? nd : 0.f;
        }
        __syncthreads();
        size_t base = ((size_t)t * R_ + row) * 32;
        for (int idx = o; idx < 128; idx += 64) {
            int mat = idx >> 5, k = idx & 31;
            const float* W = (mat < 2) ? sWc2 : sWm2;
            int rb = (mat & 1) ? 32 : 0;
            float a = (mat == 0) ? sbc2[k] : (mat == 2) ? sbm2[k] : 0.f;
            #pragma unroll
            for (int i = 0; i < 32; ++i) a += s4[w][i] * W[(rb + i) * 32 + k];
            ((mat == 0) ? Pc : (mat == 1) ? Qc : (mat == 2) ? Pm : Qm)[base + k] = a;
        }
        __syncthreads();
    }
}

// ======== Phase B: adjacency matrices — R1-proven 16x16 version ====
__global__ void __launch_bounds__(256) k_pairall(
        const float* __restrict__ Pc, const float* __restrict__ Qc,
        const float* __restrict__ Pm, const float* __restrict__ Qm,
        const float* __restrict__ Wc1, const float* __restrict__ bc1,
        const float* __restrict__ Wm1, const float* __restrict__ bm1,
        float* __restrict__ out) {
    __shared__ float sPc[16][36], sQc[16][36], sPm[16][36], sQm[16][36];
    __shared__ float sWc1[32], sWm1[32];
    int z = blockIdx.z;            // t*8 + b
    int i0 = blockIdx.x * 16, j0 = blockIdx.y * 16;
    int tid = threadIdx.y * 16 + threadIdx.x;
    size_t tb = (size_t)z * N_;
    for (int l = tid; l < 128; l += 256) {   // 16 rows x 8 float4
        int r = l >> 3, q = l & 7;
        int gi = i0 + r, gj = j0 + r;
        float4 z4 = make_float4(0.f, 0.f, 0.f, 0.f);
        *(float4*)&sPc[r][4 * q] = (gi < N_) ? *(const float4*)&Pc[(tb + gi) * 32 + 4 * q] : z4;
        *(float4*)&sPm[r][4 * q] = (gi < N_) ? *(const float4*)&Pm[(tb + gi) * 32 + 4 * q] : z4;
        *(float4*)&sQc[r][4 * q] = (gj < N_) ? *(const float4*)&Qc[(tb + gj) * 32 + 4 * q] : z4;
        *(float4*)&sQm[r][4 * q] = (gj < N_) ? *(const float4*)&Qm[(tb + gj) * 32 + 4 * q] : z4;
    }
    if (tid < 32) { sWc1[tid] = Wc1[tid]; sWm1[tid] = Wm1[tid]; }
    __syncthreads();
    int i = i0 + threadIdx.y, j = j0 + threadIdx.x;
    if (i >= N_ || j >= N_) return;
    int ty = threadIdx.y, tx = threadIdx.x;
    float g0 = 0.f, g1 = 0.f, m0 = 0.f, m1 = 0.f;
    #pragma unroll
    for (int kg = 0; kg < 8; ++kg) {
        float4 pc = *(const float4*)&sPc[ty][4 * kg];
        float4 qc = *(const float4*)&sQc[tx][4 * kg];
        float4 wc = *(const float4*)&sWc1[4 * kg];
        g0 += fmaxf(pc.x + qc.x, 0.f) * wc.x + fmaxf(pc.y + qc.y, 0.f) * wc.y;
        g1 += fmaxf(pc.z + qc.z, 0.f) * wc.z + fmaxf(pc.w + qc.w, 0.f) * wc.w;
        float4 pm = *(const float4*)&sPm[ty][4 * kg];
        float4 qm = *(const float4*)&sQm[tx][4 * kg];
        float4 wm = *(const float4*)&sWm1[4 * kg];
        m0 += fmaxf(pm.x + qm.x, 0.f) * wm.x + fmaxf(pm.y + qm.y, 0.f) * wm.y;
        m1 += fmaxf(pm.z + qm.z, 0.f) * wm.z + fmaxf(pm.w + qm.w, 0.f) * wm.w;
    }
    float g = g0 + g1 + bc1[0];
    float m = m0 + m1 + bm1[0];
    out[R_ + (((size_t)z * N_ + i) * N_ + j)] = g * sigm(m);
}

// ======== A2 = A @ A — R1-proven: 128x64 tile, 256 thr, 8x4 micro, BK=32 ==
__global__ void __launch_bounds__(256) k_a2(
        const float* __restrict__ Abase, float* __restrict__ Cbase, int nmat) {
    __shared__ float Ast[32][132];   // [k][i] transposed
    __shared__ float Bs[32][68];     // [k][j]
    int bx = blockIdx.x;
    int z = bx % nmat, tl = bx / nmat;      // z fastest => XCD-local matrices
    int i0 = (tl >> 2) * 128, j0 = (tl & 3) * 64;
    const float* Az = Abase + (size_t)z * NN_;
    float* Cz = Cbase + (size_t)z * NN_;
    int tid = threadIdx.x;
    int tx = tid & 15, ty = tid >> 4;       // tx: 4-col group, ty: 8-row group
    float acc[8][4] = {};
    for (int k0 = 0; k0 < 200; k0 += 32) {
        {
            int i = tid >> 1;                 // 0..127
            int kb = (tid & 1) * 16;          // 0 or 16
            int gi = i0 + i;
            #pragma unroll
            for (int q = 0; q < 4; ++q) {
                int k = kb + q * 4;
                int gk = k0 + k;
                float4 v = make_float4(0.f, 0.f, 0.f, 0.f);
                if (gi < N_) {
                    if (gk + 3 < N_) v = *(const float4*)&Az[gi * N_ + gk];
                    else {
                        float t0 = (gk + 0 < N_) ? Az[gi * N_ + gk + 0] : 0.f;
                        float t1 = (gk + 1 < N_) ? Az[gi * N_ + gk + 1] : 0.f;
                        float t2 = (gk + 2 < N_) ? Az[gi * N_ + gk + 2] : 0.f;
                        float t3 = (gk + 3 < N_) ? Az[gi * N_ + gk + 3] : 0.f;
                        v = make_float4(t0, t1, t2, t3);
                    }
                }
                Ast[k + 0][i] = v.x; Ast[k + 1][i] = v.y;
                Ast[k + 2][i] = v.z; Ast[k + 3][i] = v.w;
            }
        }
        {
            #pragma unroll
            for (int q = 0; q < 2; ++q) {
                int id = tid + 256 * q;       // 0..511
                int k = id >> 4, jq = (id & 15) * 4;
                int gk = k0 + k, gj = j0 + jq;
                float4 v = make_float4(0.f, 0.f, 0.f, 0.f);
                if (gk < N_) {
                    if (gj + 3 < N_) v = *(const float4*)&Az[gk * N_ + gj];
                    else {
                        float t0 = (gj + 0 < N_) ? Az[gk * N_ + gj + 0] : 0.f;
                        float t1 = (gj + 1 < N_) ? Az[gk * N_ + gj + 1] : 0.f;
                        float t2 = (gj + 2 < N_) ? Az[gk * N_ + gj + 2] : 0.f;
                        float t3 = (gj + 3 < N_) ? Az[gk * N_ + gj + 3] : 0.f;
                        v = make_float4(t0, t1, t2, t3);
                    }
                }
                *(float4*)&Bs[k][jq] = v;
            }
        }
        __syncthreads();
        #pragma unroll 8
        for (int k = 0; k < 32; ++k) {
            float4 a0 = *(const float4*)&Ast[k][ty * 8];
            float4 a1 = *(const float4*)&Ast[k][ty * 8 + 4];
            float4 bv = *(const float4*)&Bs[k][tx * 4];
            acc[0][0] += a0.x * bv.x; acc[0][1] += a0.x * bv.y; acc[0][2] += a0.x * bv.z; acc[0][3] += a0.x * bv.w;
            acc[1][0] += a0.y * bv.x; acc[1][1] += a0.y * bv.y; acc[1][2] += a0.y * bv.z; acc[1][3] += a0.y * bv.w;
            acc[2][0] += a0.z * bv.x; acc[2][1] += a0.z * bv.y; acc[2][2] += a0.z * bv.z; acc[2][3] += a0.z * bv.w;
            acc[3][0] += a0.w * bv.x; acc[3][1] += a0.w * bv.y; acc[3][2] += a0.w * bv.z; acc[3][3] += a0.w * bv.w;
            acc[4][0] += a1.x * bv.x; acc[4][1] += a1.x * bv.y; acc[4][2] += a1.x * bv.z; acc[4][3] += a1.x * bv.w;
            acc[5][0] += a1.y * bv.x; acc[5][1] += a1.y * bv.y; acc[5][2] += a1.y * bv.z; acc[5][3] += a1.y * bv.w;
            acc[6][0] += a1.z * bv.x; acc[6][1] += a1.z * bv.y; acc[6][2] += a1.z * bv.z; acc[6][3] += a1.z * bv.w;
            acc[7][0] += a1.w * bv.x; acc[7][1] += a1.w * bv.y; acc[7][2] += a1.w * bv.z; acc[7][3] += a1.w * bv.w;
        }
        __syncthreads();
    }
    #pragma unroll
    for (int r = 0; r < 8; ++r) {
        int gi = i0 + ty * 8 + r;
        if (gi >= N_) continue;
        int gj = j0 + tx * 4;
        if (gj + 3 < N_) {
            *(float4*)&Cz[gi * N_ + gj] = make_float4(acc[r][0], acc[r][1], acc[r][2], acc[r][3]);
        } else {
            #pragma unroll
            for (int e = 0; e < 4; ++e) if (gj + e < N_) Cz[gi * N_ + gj + e] = acc[r][e];
        }
    }
}

// ======== xt-hops: xh[zl][i][4] = {A@x0, A@x1, A2@x0, A2@x1} ========
__global__ void __launch_bounds__(256) k_xh(
        const float* __restrict__ Abase, const float* __restrict__ A2base,
        const float* __restrict__ x, int z0, float* __restrict__ xh) {
    __shared__ float xtl[400];
    int zl = blockIdx.x, tid = threadIdx.x;
    int z = z0 + zl, t = z >> 3, b = z & 7;
    int w = tid >> 6, l = tid & 63;
    const float* xb = x + ((size_t)(b * T_ + t)) * N_ * 2;
    for (int idx = tid; idx < 400; idx += 256) xtl[idx] = xb[idx];
    __syncthreads();
    for (int it = 0; it < 50; ++it) {
        int i = it * 4 + w;
        float p0 = 0.f, p1 = 0.f, p2 = 0.f, p3 = 0.f;
        if (l < 50) {
            float4 a4 = *(const float4*)(Abase + (size_t)zl * NN_ + i * 200 + 4 * l);
            float4 c4 = *(const float4*)(A2base + (size_t)zl * NN_ + i * 200 + 4 * l);
            #pragma unroll
            for (int q = 0; q < 4; ++q) {
                float av = (&a4.x)[q], cv = (&c4.x)[q];
                float x0 = xtl[(4 * l + q) * 2], x1 = xtl[(4 * l + q) * 2 + 1];
                p0 += av * x0; p1 += av * x1; p2 += cv * x0; p3 += cv * x1;
            }
        }
        #pragma unroll
        for (int off = 32; off > 0; off >>= 1) {
            p0 += __shfl_down(p0, off); p1 += __shfl_down(p1, off);
            p2 += __shfl_down(p2, off); p3 += __shfl_down(p3, off);
        }
        if (l == 0) *(float4*)(xh + ((size_t)zl * N_ + i) * 4) = make_float4(p0, p1, p2, p3);
    }
}

// ======== K1: hop + ru gate. Gate restructured: thread = (c-group x k-split)
// with float4 W row loads (25 b128/thread vs 198 scalar) + LDS k-reduce.
// feat[r][0..197] mirrors W row order: [x(2) | F(64) | xhA(2) | hopA(64) |
// xhC(2) | hopC(64)].
__global__ void __launch_bounds__(256) k_ru2(
        const float* __restrict__ At, const float* __restrict__ A2t,
        const float* __restrict__ xht,
        const float* __restrict__ x, int t, const float* __restrict__ state,
        const float* __restrict__ Wru, const float* __restrict__ bru,
        float* __restrict__ rs, float* __restrict__ ub) {
    __shared__ float a2s[2 * 200], c2s[2 * 200];
    __shared__ float hpA[4][64], hpC[4][64];
    __shared__ float feat[2][200];
    __shared__ float gp[8][2][128];
    int bx = blockIdx.x;
    int b = bx & 7, i0 = (bx >> 3) * 2;      // b == XCD -> state stays L2-local
    int tid = threadIdx.x;
    const float* F = state + (size_t)b * (N_ * 64);
    {   // stage: A rows, F rows -> feat[.][2..65], x -> feat[.][0..1], xh
        const float4* Ar = (const float4*)(At + ((size_t)b * N_ + i0) * 200);
        const float4* Cr = (const float4*)(A2t + ((size_t)b * N_ + i0) * 200);
        if (tid < 100) { ((float4*)a2s)[tid] = Ar[tid]; ((float4*)c2s)[tid] = Cr[tid]; }
        if (tid >= 100 && tid < 164) {       // 2 rows x 32 float2
            int l = tid - 100, r = l >> 5, q = l & 31;
            *(float2*)&feat[r][2 + 2 * q] = *(const float2*)&F[(size_t)(i0 + r) * 64 + 2 * q];
        }
        if (tid >= 164 && tid < 168) {
            int l = tid - 164;
            feat[l >> 1][l & 1] = x[((size_t)(b * T_ + t) * N_ + i0 + (l >> 1)) * 2 + (l & 1)];
        }
        if (tid >= 168 && tid < 176) {
            int l = tid - 168, rr = l >> 2, q = l & 3;
            feat[rr][(q < 2) ? (66 + q) : (132 + q - 2)] = xht[((size_t)b * N_ + i0 + rr) * 4 + q];
        }
    }
    __syncthreads();
    {   // hop (unchanged from R5): wave = (h<<1)|r, lanes = 16 cg x 4 jq
        int w = tid >> 6, lane = tid & 63;
        int r = w & 1, h = w >> 1;
        int cg = lane & 15, jq = lane >> 4;
        const float* ar = a2s + r * 200 + h * 100;
        const float* cr = c2s + r * 200 + h * 100;
        const float* Fb = F + (size_t)(h * 100) * 64 + 4 * cg;
        float4 accA = make_float4(0.f, 0.f, 0.f, 0.f);
        float4 accC = make_float4(0.f, 0.f, 0.f, 0.f);
        #pragma unroll 5
        for (int m = 0; m < 25; ++m) {
            int j = jq + 4 * m;
            float av = ar[j], cv = cr[j];
            float4 f4 = *(const float4*)&Fb[(size_t)j * 64];
            accA.x += av * f4.x; accA.y += av * f4.y; accA.z += av * f4.z; accA.w += av * f4.w;
            accC.x += cv * f4.x; accC.y += cv * f4.y; accC.z += cv * f4.z; accC.w += cv * f4.w;
        }
        accA.x += __shfl_xor(accA.x, 16); accA.y += __shfl_xor(accA.y, 16);
        accA.z += __shfl_xor(accA.z, 16); accA.w += __shfl_xor(accA.w, 16);
        accC.x += __shfl_xor(accC.x, 16); accC.y += __shfl_xor(accC.y, 16);
        accC.z += __shfl_xor(accC.z, 16); accC.w += __shfl_xor(accC.w, 16);
        accA.x += __shfl_xor(accA.x, 32); accA.y += __shfl_xor(accA.y, 32);
        accA.z += __shfl_xor(accA.z, 32); accA.w += __shfl_xor(accA.w, 32);
        accC.x += __shfl_xor(accC.x, 32); accC.y += __shfl_xor(accC.y, 32);
        accC.z += __shfl_xor(accC.z, 32); accC.w += __shfl_xor(accC.w, 32);
        if (lane < 16) {
            *(float4*)&hpA[w][4 * cg] = accA;
            *(float4*)&hpC[w][4 * cg] = accC;
        }
    }
    __syncthreads();
    {   // combine halves into feat
        int mt = tid >> 7, r = (tid >> 6) & 1, c = tid & 63;
        float v = mt ? (hpC[r][c] + hpC[2 + r][c]) : (hpA[r][c] + hpA[2 + r][c]);
        feat[r][(mt ? 134 : 68) + c] = v;
    }
    __syncthreads();
    {   // gate partial: cq = c-group (4 cols), kh = k-split (8 x ~25 rows)
        int cq = tid & 31, kh = tid >> 5;
        int k0 = 25 * kh, kend = (k0 + 25 < 198) ? (k0 + 25) : 198;
        float4 s0 = make_float4(0.f, 0.f, 0.f, 0.f);
        float4 s1 = make_float4(0.f, 0.f, 0.f, 0.f);
        for (int k = k0; k < kend; ++k) {
            float4 w4 = *(const float4*)&Wru[(size_t)k * 128 + 4 * cq];
            float f0 = feat[0][k], f1 = feat[1][k];
            s0.x += f0 * w4.x; s0.y += f0 * w4.y; s0.z += f0 * w4.z; s0.w += f0 * w4.w;
            s1.x += f1 * w4.x; s1.y += f1 * w4.y; s1.z += f1 * w4.z; s1.w += f1 * w4.w;
        }
        *(float4*)&gp[kh][0][4 * cq] = s0;
        *(float4*)&gp[kh][1][4 * cq] = s1;
    }
    __syncthreads();
    {   // reduce + activation + store
        int rq = tid >> 7, c = tid & 127;
        float a = bru[c];
        #pragma unroll
        for (int h = 0; h < 8; ++h) a += gp[h][rq][c];
        float v = sigm(a);
        size_t go = (size_t)b * N_ + i0 + rq;
        if (c < 64) rs[go * 64 + c] = v * feat[rq][2 + c];
        else        ub[go * 64 + (c - 64)] = v;
    }
}

// ======== K2: same structure; cand gate = 16 k-splits x 16 c-groups ========
__global__ void __launch_bounds__(256) k_cand2(
        const float* __restrict__ At, const float* __restrict__ A2t,
        const float* __restrict__ xht,
        const float* __restrict__ x, int t, const float* __restrict__ rsin,
        const float* __restrict__ Wcd, const float* __restrict__ bcd,
        const float* __restrict__ ub, float* __restrict__ state) {
    __shared__ float a2s[2 * 200], c2s[2 * 200];
    __shared__ float hpA[4][64], hpC[4][64];
    __shared__ float feat[2][200];
    __shared__ float gp[16][2][64];
    int bx = blockIdx.x;
    int b = bx & 7, i0 = (bx >> 3) * 2;
    int tid = threadIdx.x;
    const float* F = rsin + (size_t)b * (N_ * 64);
    {
        const float4* Ar = (const float4*)(At + ((size_t)b * N_ + i0) * 200);
        const float4* Cr = (const float4*)(A2t + ((size_t)b * N_ + i0) * 200);
        if (tid < 100) { ((float4*)a2s)[tid] = Ar[tid]; ((float4*)c2s)[tid] = Cr[tid]; }
        if (tid >= 100 && tid < 164) {
            int l = tid - 100, r = l >> 5, q = l & 31;
            *(float2*)&feat[r][2 + 2 * q] = *(const float2*)&F[(size_t)(i0 + r) * 64 + 2 * q];
        }
        if (tid >= 164 && tid < 168) {
            int l = tid - 164;
            feat[l >> 1][l & 1] = x[((size_t)(b * T_ + t) * N_ + i0 + (l >> 1)) * 2 + (l & 1)];
        }
        if (tid >= 168 && tid < 176) {
            int l = tid - 168, rr = l >> 2, q = l & 3;
            feat[rr][(q < 2) ? (66 + q) : (132 + q - 2)] = xht[((size_t)b * N_ + i0 + rr) * 4 + q];
        }
    }
    __syncthreads();
    {   // hop
        int w = tid >> 6, lane = tid & 63;
        int r = w & 1, h = w >> 1;
        int cg = lane & 15, jq = lane >> 4;
        const float* ar = a2s + r * 200 + h * 100;
        const float* cr = c2s + r * 200 + h * 100;
        const float* Fb = F + (size_t)(h * 100) * 64 + 4 * cg;
        float4 accA = make_float4(0.f, 0.f, 0.f, 0.f);
        float4 accC = make_float4(0.f, 0.f, 0.f, 0.f);
        #pragma unroll 5
        for (int m = 0; m < 25; ++m) {
            int j = jq + 4 * m;
            float av = ar[j], cv = cr[j];
            float4 f4 = *(const float4*)&Fb[(size_t)j * 64];
            accA.x += av * f4.x; accA.y += av * f4.y; accA.z += av * f4.z; accA.w += av * f4.w;
            accC.x += cv * f4.x; accC.y += cv * f4.y; accC.z += cv * f4.z; accC.w += cv * f4.w;
        }
        accA.x += __shfl_xor(accA.x, 16); accA.y += __shfl_xor(accA.y, 16);
        accA.z += __shfl_xor(accA.z, 16); accA.w += __shfl_xor(accA.w, 16);
        accC.x += __shfl_xor(accC.x, 16); accC.y += __shfl_xor(accC.y, 16);
        accC.z += __shfl_xor(accC.z, 16); accC.w += __shfl_xor(accC.w, 16);
        accA.x += __shfl_xor(accA.x, 32); accA.y += __shfl_xor(accA.y, 32);
        accA.z += __shfl_xor(accA.z, 32); accA.w += __shfl_xor(accA.w, 32);
        accC.x += __shfl_xor(accC.x, 32); accC.y += __shfl_xor(accC.y, 32);
        accC.z += __shfl_xor(accC.z, 32); accC.w += __shfl_xor(accC.w, 32);
        if (lane < 16) {
            *(float4*)&hpA[w][4 * cg] = accA;
            *(float4*)&hpC[w][4 * cg] = accC;
        }
    }
    __syncthreads();
    {
        int mt = tid >> 7, r = (tid >> 6) & 1, c = tid & 63;
        float v = mt ? (hpC[r][c] + hpC[2 + r][c]) : (hpA[r][c] + hpA[2 + r][c]);
        feat[r][(mt ? 134 : 68) + c] = v;
    }
    __syncthreads();
    {   // gate partial: 16 c-groups x 16 k-splits (13 rows each)
        int cq = tid & 15, kh = tid >> 4;
        int k0 = 13 * kh, kend = (k0 + 13 < 198) ? (k0 + 13) : 198;
        float4 s0 = make_float4(0.f, 0.f, 0.f, 0.f);
        float4 s1 = make_float4(0.f, 0.f, 0.f, 0.f);
        for (int k = k0; k < kend; ++k) {
            float4 w4 = *(const float4*)&Wcd[(size_t)k * 64 + 4 * cq];
            float f0 = feat[0][k], f1 = feat[1][k];
            s0.x += f0 * w4.x; s0.y += f0 * w4.y; s0.z += f0 * w4.z; s0.w += f0 * w4.w;
            s1.x += f1 * w4.x; s1.y += f1 * w4.y; s1.z += f1 * w4.z; s1.w += f1 * w4.w;
        }
        *(float4*)&gp[kh][0][4 * cq] = s0;
        *(float4*)&gp[kh][1][4 * cq] = s1;
    }
    __syncthreads();
    if (tid < 128) {
        int rq = tid >> 6, c = tid & 63;
        float a = bcd[c];
        #pragma unroll
        for (int h = 0; h < 16; ++h) a += gp[h][rq][c];
        size_t go = (size_t)b * N_ + i0 + rq;
        float cnd = tanhf(a);
        float u = ub[go * 64 + c];
        float st = state[go * 64 + c];
        state[go * 64 + c] = u * st + (1.f - u) * cnd;
    }
}

// ======== pred head ========
__global__ void __launch_bounds__(64) k_pred(
        const float* __restrict__ state,
        const float* __restrict__ Wp1, const float* __restrict__ bp1,
        const float* __restrict__ Wp2, const float* __restrict__ bp2,
        float* __restrict__ out) {
    __shared__ float st[64];
    int row = blockIdx.x;
    int tid = threadIdx.x;
    st[tid] = state[row * 64 + tid];
    __syncthreads();
    float acc = bp1[tid];
    #pragma unroll 8
    for (int a = 0; a < 64; ++a) acc += st[a] * Wp1[a * 64 + tid];
    acc = acc > 0.f ? acc : 0.01f * acc;
    float v = acc * Wp2[tid];
    #pragma unroll
    for (int off = 32; off > 0; off >>= 1) v += __shfl_down(v, off);
    if (tid == 0) out[row] = v + bp2[0];
}

extern "C" void kernel_launch(void* const* d_in, const int* in_sizes, int n_in,
                              void* d_out, int out_size, void* d_ws, size_t ws_size,
                              hipStream_t stream) {
    const float* x    = (const float*)d_in[0];
    const float* nf   = (const float*)d_in[1];
    const float* Ws2d = (const float*)d_in[2];
    const float* bs2d = (const float*)d_in[3];
    const float* Wrz  = (const float*)d_in[4];
    const float* brz  = (const float*)d_in[5];
    const float* Wh   = (const float*)d_in[6];
    const float* bh   = (const float*)d_in[7];
    const float* Wc2  = (const float*)d_in[8];
    const float* bc2  = (const float*)d_in[9];
    const float* Wc1  = (const float*)d_in[10];
    const float* bc1  = (const float*)d_in[11];
    const float* Wm2  = (const float*)d_in[12];
    const float* bm2  = (const float*)d_in[13];
    const float* Wm1  = (const float*)d_in[14];
    const float* bm1  = (const float*)d_in[15];
    const float* Wru  = (const float*)d_in[16];
    const float* bru  = (const float*)d_in[17];
    const float* Wcand= (const float*)d_in[18];
    const float* bcand= (const float*)d_in[19];
    const float* Wp1  = (const float*)d_in[20];
    const float* bp1  = (const float*)d_in[21];
    const float* Wp2  = (const float*)d_in[22];
    const float* bp2  = (const float*)d_in[23];
    float* out = (float*)d_out;

    float* ws = (float*)d_ws;
    const size_t PQ = (size_t)T_ * R_ * 32;
    float* Pc = ws;
    float* Qc = Pc + PQ;
    float* Pm = Qc + PQ;
    float* Qm = Pm + PQ;

    const size_t A2F = (size_t)96 * NN_;
    const size_t XHF = (size_t)96 * N_ * 4;
    const size_t FULL_NEED = (A2F + XHF + 3 * (size_t)R_ * 64) * 4;
    bool full = ws_size >= FULL_NEED;

    const float* Aall = out + R_;

    if (full) {
        float* A2base = ws;                  // aliases dead P/Q after k_pairall
        float* xhbase = ws + A2F;
        float* state  = xhbase + XHF;
        float* rs     = state + (size_t)R_ * 64;
        float* ub     = rs + (size_t)R_ * 64;

        k_dyall<<<400, 256, 0, stream>>>(x, nf, Ws2d, bs2d, Wrz, brz, Wh, bh,
                                         Wc2, Wm2, bc2, bm2, Pc, Qc, Pm, Qm, state);
        k_pairall<<<dim3(13, 13, 96), dim3(16, 16), 0, stream>>>(
            Pc, Qc, Pm, Qm, Wc1, bc1, Wm1, bm1, out);
        k_a2<<<96 * 8, 256, 0, stream>>>(Aall, A2base, 96);
        k_xh<<<96, 256, 0, stream>>>(Aall, A2base, x, 0, xhbase);

        for (int t = 0; t < T_; ++t) {
            const float* At  = Aall + (size_t)t * 8 * NN_;
            const float* A2t = A2base + (size_t)t * 8 * NN_;
            const float* xht = xhbase + (size_t)t * 8 * N_ * 4;
            k_ru2  <<<800, 256, 0, stream>>>(At, A2t, xht, x, t, state, Wru, bru, rs, ub);
            k_cand2<<<800, 256, 0, stream>>>(At, A2t, xht, x, t, rs, Wcand, bcand, ub, state);
        }
        k_pred<<<R_, 64, 0, stream>>>(state, Wp1, bp1, Wp2, bp2, out);
    } else {
        float* A2base = ws + 4 * PQ;
        float* xhbase = A2base + (size_t)8 * NN_;
        float* state  = xhbase + (size_t)8 * N_ * 4;
        float* rs     = state + (size_t)R_ * 64;
        float* ub     = rs + (size_t)R_ * 64;

        k_dyall<<<400, 256, 0, stream>>>(x, nf, Ws2d, bs2d, Wrz, brz, Wh, bh,
                                         Wc2, Wm2, bc2, bm2, Pc, Qc, Pm, Qm, state);
        k_pairall<<<dim3(13, 13, 96), dim3(16, 16), 0, stream>>>(
            Pc, Qc, Pm, Qm, Wc1, bc1, Wm1, bm1, out);
        for (int t = 0; t < T_; ++t) {
            const float* At = Aall + (size_t)t * 8 * NN_;
            k_a2<<<8 * 8, 256, 0, stream>>>(At, A2base, 8);
            k_xh<<<8, 256, 0, stream>>>(At, A2base, x, t * 8, xhbase);
            k_ru2  <<<800, 256, 0, stream>>>(At, A2base, xhbase, x, t, state, Wru, bru, rs, ub);
            k_cand2<<<800, 256, 0, stream>>>(At, A2base, xhbase, x, t, rs, Wcand, bcand, ub, state);
        }
        k_pred<<<R_, 64, 0, stream>>>(state, Wp1, bp1, Wp2, bp2, out);
    }
}